// Round 2
// 910.208 us; speedup vs baseline: 1.2214x; 1.2214x over previous
//
#include <hip/hip_runtime.h>

#define IN_CH 4096
#define OUT_CH 4096
#define BATCH 16384

typedef __attribute__((ext_vector_type(8))) short bf16x8;
typedef __attribute__((ext_vector_type(4))) float f32x4;
typedef __attribute__((ext_vector_type(8))) unsigned short us8;

__device__ __forceinline__ unsigned short f2bf(float f) {
    union { float f; unsigned int u; } v; v.f = f;
    unsigned int u = v.u;
    unsigned int r = (u + 0x7fffu + ((u >> 16) & 1u)) >> 16;  // RNE
    return (unsigned short)r;
}

// ---- pass 1: last-occurrence-wins via atomicMax of (i+1); 0 = empty ----
__global__ void scatter_max(const int* __restrict__ rows, const int* __restrict__ cols,
                            int* __restrict__ idx, int nnz) {
    int i = blockIdx.x * blockDim.x + threadIdx.x;
    if (i < nnz) {
        atomicMax(&idx[(size_t)rows[i] * IN_CH + cols[i]], i + 1);
    }
}

// ---- pass 2: winner writes its (bf16) weight ----
__global__ void scatter_write(const int* __restrict__ rows, const int* __restrict__ cols,
                              const float* __restrict__ w, const int* __restrict__ idx,
                              unsigned short* __restrict__ W, int nnz) {
    int i = blockIdx.x * blockDim.x + threadIdx.x;
    if (i < nnz) {
        size_t cell = (size_t)rows[i] * IN_CH + cols[i];
        if (idx[cell] == i + 1) W[cell] = f2bf(w[i]);
    }
}

// ---- x f32 -> bf16, 8 elems/thread ----
__global__ void convert_x(const float* __restrict__ x, unsigned short* __restrict__ xb) {
    size_t i = ((size_t)blockIdx.x * blockDim.x + threadIdx.x) * 8;
    float4 f0 = *(const float4*)(x + i);
    float4 f1 = *(const float4*)(x + i + 4);
    us8 o;
    o[0] = f2bf(f0.x); o[1] = f2bf(f0.y); o[2] = f2bf(f0.z); o[3] = f2bf(f0.w);
    o[4] = f2bf(f1.x); o[5] = f2bf(f1.y); o[6] = f2bf(f1.z); o[7] = f2bf(f1.w);
    *(us8*)(xb + i) = o;
}

__device__ __forceinline__ void gl_lds16(const unsigned short* g, unsigned short* l) {
    __builtin_amdgcn_global_load_lds(
        (const __attribute__((address_space(1))) unsigned int*)g,
        (__attribute__((address_space(3))) unsigned int*)l,
        16, 0, 0);
}

// ============================================================================
// 256x256 tile, BK=64, 512 threads (8 waves 2Mx4N), 8-phase counted-vmcnt
// schedule.  STAGING UNITS == READ-HALVES (death units), fixing the r1 WAR
// race where row-half staging clobbered rows still needed one phase later.
//
// LDS (ushort units): buf b at b*32768; A tile at +0 (16384), B at +16384.
// Row r of a tile at +r*64; logical 16B-chunk c of row r at physical
// chunk c ^ (r&7) (T2 swizzle; global SOURCE pre-swizzled, LDS dest linear,
// read side applies the same XOR — both-sides-or-neither).
//
// Read-halves (die in one phase each):
//   A-RH0 = rows {0-63, 128-191}   (read at mh=0 phase: wm=0 | wm=1)
//   A-RH1 = rows {64-127, 192-255} (mh=1)
//   B-RH0 = rows {0-31,64-95,128-159,192-223}  (nh=0, wn=0..3)
//   B-RH1 = +32 rows                            (nh=1)
// One STAGE = 2 x global_load_lds, per-wave LDS base picks the stripe:
//   A: wave w rows w*8 (+128 in call 2);  B: rB=(w&3)*8+(w>>2)*64 (+128).
//
// Phase j: ds-read one read-half -> regs | stage one read-half | s_barrier |
// lgkmcnt(0) | 16 MFMA (setprio 1) | s_barrier.  vmcnt(6) only at j=3/j=7.
// Stage targets the region that died last phase (WAR safe: issued after the
// barrier that proves all waves' reads retired).  Ledger (2 loads/phase):
// VMC(6)@j3 completes through j0 => O-tile fully landed before j4 read;
// VMC(6)@j7 completes through j4 => next E-tile landed before j0 read.
// MFMA quadrant order per tile (ds at r..r+3): Q00@r+1 Q10@r+2 Q01@r+3
// Q11@r+4 -> single-buffered register fragments.
// ============================================================================
#define BAR()   asm volatile("s_barrier" ::: "memory")
#define LGKM0() asm volatile("s_waitcnt lgkmcnt(0)" ::: "memory")
#define VMC(n)  asm volatile("s_waitcnt vmcnt(" #n ")" ::: "memory")

#define STAGE_A(gsrc, ldst) do {                                            \
    gl_lds16((gsrc) + gAoff, ldsA_w + (ldst));                              \
    gl_lds16((gsrc) + gAoff + (size_t)128 * IN_CH, ldsA_w + (ldst) + 8192); \
} while (0)

#define STAGE_B(gsrc, ldst) do {                                            \
    gl_lds16((gsrc) + gBoff, ldsB_w + (ldst));                              \
    gl_lds16((gsrc) + gBoff + (size_t)128 * IN_CH, ldsB_w + (ldst) + 8192); \
} while (0)

#define LD_A(dst, bufbase, mh) do { _Pragma("unroll")                       \
    for (int mt = 0; mt < 4; ++mt) {                                        \
        dst[mt][0] = *(const bf16x8*)(lds + (bufbase) + (mh)*4096 + aRow + mt*1024 + axk0); \
        dst[mt][1] = *(const bf16x8*)(lds + (bufbase) + (mh)*4096 + aRow + mt*1024 + axk1); \
    } } while (0)

#define LD_B(dst, bufbase, nh) do { _Pragma("unroll")                       \
    for (int nt = 0; nt < 2; ++nt) {                                        \
        dst[nt][0] = *(const bf16x8*)(lds + (bufbase) + (nh)*2048 + bRow + nt*1024 + axk0); \
        dst[nt][1] = *(const bf16x8*)(lds + (bufbase) + (nh)*2048 + bRow + nt*1024 + axk1); \
    } } while (0)

#define MFMA_Q(mh, nh, aF, bF) do {                                         \
    __builtin_amdgcn_s_setprio(1);                                          \
    _Pragma("unroll") for (int mt = 0; mt < 4; ++mt)                        \
    _Pragma("unroll") for (int nt = 0; nt < 2; ++nt)                        \
    _Pragma("unroll") for (int kk = 0; kk < 2; ++kk)                        \
        acc[(mh)*4+mt][(nh)*2+nt] = __builtin_amdgcn_mfma_f32_16x16x32_bf16( \
            aF[mt][kk], bF[nt][kk], acc[(mh)*4+mt][(nh)*2+nt], 0, 0, 0);    \
    __builtin_amdgcn_s_setprio(0);                                          \
} while (0)

__global__ __launch_bounds__(512, 2) void gemm_bt(
    const unsigned short* __restrict__ A,   // x_bf16 [BATCH][IN_CH]
    const unsigned short* __restrict__ B,   // W_bf16 [OUT_CH][IN_CH]
    const float* __restrict__ bias,         // [OUT_CH]
    float* __restrict__ C)                  // [BATCH][OUT_CH]
{
    __shared__ unsigned short lds[65536];   // 128 KiB
    const int tid  = threadIdx.x;
    const int wave = tid >> 6;
    const int lane = tid & 63;
    const int ml   = lane & 15;
    const int quad = lane >> 4;
    const int wm   = wave >> 2;             // 0..1
    const int wn   = wave & 3;              // 0..3

    // T1: XCD-aware swizzle (1024 wgs, 8 XCDs, bijective since 1024%8==0)
    const int swz = (blockIdx.x & 7) * 128 + (blockIdx.x >> 3);
    const int bm = swz >> 4;                // 0..63
    const int bn = swz & 15;                // 0..15

    // staging: within a wave's 8-row stripe, lane covers (lrow = lane>>3,
    // physical chunk = lane&7); global source fetches logical chunk
    // (lane&7) ^ lrow  (row&7 == lrow for all stripe bases, multiples of 8).
    const int lrow = lane >> 3;
    const int lchk = (lane & 7) ^ lrow;
    const int rA = wave * 8;                            // A stripe base row
    const int rB = (wave & 3) * 8 + (wave >> 2) * 64;   // B stripe base row
    const size_t gAoff = (size_t)(rA + lrow) * IN_CH + lchk * 8;
    const size_t gBoff = (size_t)(rB + lrow) * IN_CH + lchk * 8;
    unsigned short* ldsA_w = lds + rA * 64;             // wave-uniform bases
    unsigned short* ldsB_w = lds + rB * 64;

    const unsigned short* gA = A + (size_t)bm * 256 * IN_CH;
    const unsigned short* gB = B + (size_t)bn * 256 * IN_CH;

    // ds-read per-thread bases (ushort units); row&7 == ml&7 everywhere.
    const int axk0 = ((quad)     ^ (ml & 7)) * 8;   // kk=0 logical chunk = quad
    const int axk1 = ((quad ^ 4) ^ (ml & 7)) * 8;   // kk=1 logical chunk = 4+quad
    const int aRow = (wm * 128 + ml) * 64;
    const int bRow = (wn * 64  + ml) * 64;

    f32x4 acc[8][4];
#pragma unroll
    for (int i = 0; i < 8; ++i)
#pragma unroll
        for (int j = 0; j < 4; ++j) acc[i][j] = (f32x4){0.f, 0.f, 0.f, 0.f};

    bf16x8 aL[4][2], aH[4][2], bL[2][2], bH[2][2];
    const bf16x8 zf = (bf16x8){0, 0, 0, 0, 0, 0, 0, 0};
#pragma unroll
    for (int mt = 0; mt < 4; ++mt) { aH[mt][0] = zf; aH[mt][1] = zf; }
#pragma unroll
    for (int nt = 0; nt < 2; ++nt) { bH[nt][0] = zf; bH[nt][1] = zf; }

    // ---- prologue: T0 (all 4 read-halves) -> buf0, T1 {A-RH0,B-RH0,A-RH1}
    //      -> buf1; T1.B-RH1 staged at loop i=0 j=0.
    STAGE_A(gA,                            0);                  // T0.A-RH0
    STAGE_B(gB,                            16384);              // T0.B-RH0
    STAGE_A(gA + (size_t)64 * IN_CH,       4096);               // T0.A-RH1
    STAGE_B(gB + (size_t)32 * IN_CH,       16384 + 2048);       // T0.B-RH1
    STAGE_A(gA + 64,                       32768);              // T1.A-RH0
    STAGE_B(gB + 64,                       32768 + 16384);      // T1.B-RH0
    STAGE_A(gA + 64 + (size_t)64 * IN_CH,  32768 + 4096);       // T1.A-RH1
    VMC(6);          // T0 fully landed (T1's 3 staged halves in flight)
    BAR();

    // ---- main loop: iteration i computes E=2i (buf0), O=2i+1 (buf1)
#pragma unroll 1
    for (int i = 0; i < 31; ++i) {
        const size_t k2i = (size_t)i * 128;          // k-base of tile 2i

        // j=0: ds E.A-RH0 | stage O.B-RH1 (region died i-1 j7) | Q11 prev O
        LD_A(aL, 0, 0);
        STAGE_B(gB + k2i + 64 + (size_t)32 * IN_CH, 32768 + 16384 + 2048);
        BAR(); LGKM0();
        MFMA_Q(1, 1, aH, bH);
        BAR();
        // j=1: ds E.B-RH0 | stage T2.A-RH0 (died j0) | E.Q00
        LD_B(bL, 16384, 0);
        STAGE_A(gA + k2i + 128, 0);
        BAR(); LGKM0();
        MFMA_Q(0, 0, aL, bL);
        BAR();
        // j=2: ds E.A-RH1 | stage T2.B-RH0 (died j1) | E.Q10
        LD_A(aH, 0, 1);
        STAGE_B(gB + k2i + 128, 16384);
        BAR(); LGKM0();
        MFMA_Q(1, 0, aH, bL);
        BAR();
        // j=3: ds E.B-RH1 | stage T2.A-RH1 (died j2) | vmcnt(6): O landed | E.Q01
        LD_B(bH, 16384, 1);
        STAGE_A(gA + k2i + 128 + (size_t)64 * IN_CH, 4096);
        VMC(6);
        BAR(); LGKM0();
        MFMA_Q(0, 1, aL, bH);
        BAR();
        // j=4: ds O.A-RH0 | stage T2.B-RH1 (died j3) | E.Q11
        LD_A(aL, 32768, 0);
        STAGE_B(gB + k2i + 128 + (size_t)32 * IN_CH, 16384 + 2048);
        BAR(); LGKM0();
        MFMA_Q(1, 1, aH, bH);
        BAR();
        // j=5: ds O.B-RH0 | stage T3.A-RH0 (died j4) | O.Q00
        LD_B(bL, 32768 + 16384, 0);
        STAGE_A(gA + k2i + 192, 32768);
        BAR(); LGKM0();
        MFMA_Q(0, 0, aL, bL);
        BAR();
        // j=6: ds O.A-RH1 | stage T3.B-RH0 (died j5) | O.Q10
        LD_A(aH, 32768, 1);
        STAGE_B(gB + k2i + 192, 32768 + 16384);
        BAR(); LGKM0();
        MFMA_Q(1, 0, aH, bL);
        BAR();
        // j=7: ds O.B-RH1 | stage T3.A-RH1 (died j6) | vmcnt(6): T2 landed | O.Q01
        LD_B(bH, 32768 + 16384, 1);
        STAGE_A(gA + k2i + 192 + (size_t)64 * IN_CH, 32768 + 4096);
        VMC(6);
        BAR(); LGKM0();
        MFMA_Q(0, 1, aL, bH);
        BAR();
    }

    // ---- epilogue: tiles 62 (buf0), 63 (buf1); only T63.B-RH1 left to stage
    {
        // j=0
        LD_A(aL, 0, 0);
        STAGE_B(gB + 4032 + (size_t)32 * IN_CH, 32768 + 16384 + 2048); // T63.B-RH1
        BAR(); LGKM0();
        MFMA_Q(1, 1, aH, bH);               // T61.Q11
        BAR();
        // j=1
        LD_B(bL, 16384, 0);
        BAR(); LGKM0();
        MFMA_Q(0, 0, aL, bL);
        BAR();
        // j=2
        LD_A(aH, 0, 1);
        BAR(); LGKM0();
        MFMA_Q(1, 0, aH, bL);
        BAR();
        // j=3
        LD_B(bH, 16384, 1);
        VMC(0);                              // drain: T63 fully landed
        BAR(); LGKM0();
        MFMA_Q(0, 1, aL, bH);
        BAR();
        // j=4
        LD_A(aL, 32768, 0);
        BAR(); LGKM0();
        MFMA_Q(1, 1, aH, bH);               // T62.Q11
        BAR();
        // j=5
        LD_B(bL, 32768 + 16384, 0);
        BAR(); LGKM0();
        MFMA_Q(0, 0, aL, bL);
        BAR();
        // j=6
        LD_A(aH, 32768, 1);
        BAR(); LGKM0();
        MFMA_Q(1, 0, aH, bL);
        BAR();
        // j=7
        LD_B(bH, 32768 + 16384, 1);
        LGKM0();
        MFMA_Q(0, 1, aL, bH);               // T63.Q01
        MFMA_Q(1, 1, aH, bH);               // T63.Q11
    }

    // ---- C write: D row = quad*4 + r, col = ml per 16x16 fragment
    const int gm0 = bm * 256 + wm * 128;
    const int gn0 = bn * 256 + wn * 64;
#pragma unroll
    for (int nf = 0; nf < 4; ++nf) {
        const int gn = gn0 + nf * 16 + ml;
        const float bv = bias[gn];
#pragma unroll
        for (int mf = 0; mf < 8; ++mf) {
            const int gm = gm0 + mf * 16 + quad * 4;
#pragma unroll
            for (int r = 0; r < 4; ++r)
                C[(size_t)(gm + r) * OUT_CH + gn] = acc[mf][nf][r] + bv;
        }
    }
}

extern "C" void kernel_launch(void* const* d_in, const int* in_sizes, int n_in,
                              void* d_out, int out_size, void* d_ws, size_t ws_size,
                              hipStream_t stream) {
    const float* x    = (const float*)d_in[0];
    const float* sw   = (const float*)d_in[1];
    const float* bias = (const float*)d_in[2];
    const int*   rows = (const int*)d_in[3];
    const int*   cols = (const int*)d_in[4];
    const int    nnz  = in_sizes[1];

    char* base = (char*)d_ws;
    unsigned short* W  = (unsigned short*)base;                                   // [0, 32MB)
    int*            idx = (int*)(base + (size_t)OUT_CH * IN_CH * 2);              // [32MB, 96MB)
    unsigned short* xb  = (unsigned short*)(base + (size_t)OUT_CH * IN_CH * 2);   // [32MB, 160MB) — overwrites idx AFTER scatter

    // W = 0 (bf16 zero == 0x0000) and idx = 0 (empty sentinel) in one memset
    hipMemsetAsync(d_ws, 0, (size_t)OUT_CH * IN_CH * 2 + (size_t)OUT_CH * IN_CH * 4, stream);
    hipLaunchKernelGGL(scatter_max, dim3((nnz + 255) / 256), dim3(256), 0, stream,
                       rows, cols, idx, nnz);
    hipLaunchKernelGGL(scatter_write, dim3((nnz + 255) / 256), dim3(256), 0, stream,
                       rows, cols, sw, idx, W, nnz);
    hipLaunchKernelGGL(convert_x, dim3(32768), dim3(256), 0, stream, x, xb);
    hipLaunchKernelGGL(gemm_bt, dim3(1024), dim3(512), 0, stream, xb, W, bias, (float*)d_out);
}